// Round 1
// baseline (381.710 us; speedup 1.0000x reference)
//
#include <hip/hip_runtime.h>

// Problem constants (fixed by the reference):
#define B_ 8
#define S_ 8192
#define D_ 768
#define V_ 64
#define L_ 26

typedef __attribute__((ext_vector_type(8))) short short8;   // 8 bf16 (4 VGPRs)
typedef __attribute__((ext_vector_type(4))) float floatx4;  // MFMA C/D

#define TOKS 512               // tokens (K) per work item
#define SLICES (S_ / TOKS)     // 16 K-slices -> partial-sum planes
#define NSL  48                // d-columns (N) per wave = 3 tiles of 16
#define NITEMS 512             // SLICES * 4 (d-ranges) * B_

// Fused: pool (MFMA one-hot segment-sum) -> device spin barrier -> reduce+classify.
// Pool phase identical math to the 2-kernel version (hi/lo bf16 split, exact
// one-hot A, fp32 MFMA accumulate). Barrier: tid0 __threadfence (buffer_wbl2:
// flushes part to L3) + device-scope atomic arrive/spin; all blocks co-resident
// (grid = min(2*numCU, 512), __launch_bounds__(256,2), ~4KB LDS). Reduce phase
// then reads part from L3/L2 instead of a second-kernel HBM round trip.
__global__ __launch_bounds__(256, 2) void fused_kernel(
    const float* __restrict__ h, const int* __restrict__ ids,
    const float* __restrict__ Wm, const float* __restrict__ bias,
    float* __restrict__ out,
    float* __restrict__ part, unsigned int* __restrict__ cntpart,
    unsigned int* __restrict__ bar, int nblk)
{
    __shared__ unsigned int cnt[V_];
    __shared__ float mean[D_];
    __shared__ unsigned int scnt;

    const int tid  = threadIdx.x;
    const int lane = tid & 63;
    const int wave = tid >> 6;
    const int nl   = lane & 15;   // n (B) / m (A) index within a 16-tile
    const int quad = lane >> 4;   // k-quadrant: lane covers k = quad*8 + j

    // ---------------- pool phase: work items = (slice, y, b) ----------------
    for (int item = blockIdx.x; item < NITEMS; item += nblk) {
        const int slice = item & (SLICES - 1);
        const int y     = (item >> 4) & 3;
        const int b     = item >> 6;
        const int k0    = slice * TOKS;
        const int n0    = y * (4 * NSL) + wave * NSL;

        const int*   idrow = ids + b * S_ + k0;
        const float* hrow  = h + ((size_t)b * S_ + k0) * D_ + n0;

        // Per-slice histogram (only the y==0 items; non-atomic flush).
        if (y == 0) {
            __syncthreads();                  // cnt[] reuse guard across items
            if (tid < V_) cnt[tid] = 0u;
            __syncthreads();
            if (tid < TOKS / 4) {
                const int4 q = ((const int4*)idrow)[tid];
                atomicAdd(&cnt[q.x], 1u); atomicAdd(&cnt[q.y], 1u);
                atomicAdd(&cnt[q.z], 1u); atomicAdd(&cnt[q.w], 1u);
            }
            __syncthreads();
            if (tid < V_) cntpart[(slice * B_ + b) * V_ + tid] = cnt[tid];
        }

        floatx4 acc[4][3];
        #pragma unroll
        for (int mt = 0; mt < 4; ++mt)
            #pragma unroll
            for (int nt = 0; nt < 3; ++nt) acc[mt][nt] = (floatx4)0.f;

        for (int ks = 0; ks < TOKS; ks += 32) {
            const int kb = ks + quad * 8;
            // this quad's 8 token ids (two aligned int4 loads, L1-broadcast)
            const int4* ip = (const int4*)(idrow + kb);
            const int4 i0 = ip[0], i1 = ip[1];
            const int idv[8] = {i0.x, i0.y, i0.z, i0.w, i1.x, i1.y, i1.z, i1.w};

            // A fragments (one-hot, exact in bf16): A[m=mt*16+nl][k=quad*8+j]
            short8 afrag[4];
            #pragma unroll
            for (int mt = 0; mt < 4; ++mt) {
                const int m = mt * 16 + nl;
                #pragma unroll
                for (int j = 0; j < 8; ++j)
                    afrag[mt][j] = (idv[j] == m) ? (short)0x3F80 : (short)0;
            }

            // B fragments per n-tile: B[k=quad*8+j][n=nt*16+nl], hi/lo bf16 split.
            // h is streamed exactly once -> nontemporal (keep part hot in L2).
            #pragma unroll
            for (int nt = 0; nt < 3; ++nt) {
                const float* bp = hrow + (size_t)kb * D_ + nt * 16 + nl;
                float f[8];
                #pragma unroll
                for (int j = 0; j < 8; ++j)
                    f[j] = __builtin_nontemporal_load(bp + (size_t)j * D_);
                short8 bhi, blo;
                #pragma unroll
                for (int j = 0; j < 8; ++j) {
                    const unsigned u = __builtin_bit_cast(unsigned, f[j]);
                    bhi[j] = (short)(u >> 16);
                    const float hif = __builtin_bit_cast(float, u & 0xFFFF0000u);
                    const float lof = f[j] - hif;
                    blo[j] = (short)(__builtin_bit_cast(unsigned, lof) >> 16);
                }
                #pragma unroll
                for (int mt = 0; mt < 4; ++mt) {
                    acc[mt][nt] = __builtin_amdgcn_mfma_f32_16x16x32_bf16(
                        afrag[mt], bhi, acc[mt][nt], 0, 0, 0);
                    acc[mt][nt] = __builtin_amdgcn_mfma_f32_16x16x32_bf16(
                        afrag[mt], blo, acc[mt][nt], 0, 0, 0);
                }
            }
        }

        // Flush partial sums (plain stores). C/D layout: col=lane&15, row=quad*4+r.
        float* pbase = part + ((size_t)(slice * B_ + b) * V_) * D_;
        #pragma unroll
        for (int mt = 0; mt < 4; ++mt)
            #pragma unroll
            for (int nt = 0; nt < 3; ++nt)
                #pragma unroll
                for (int r = 0; r < 4; ++r) {
                    const int v = mt * 16 + quad * 4 + r;
                    const int d = n0 + nt * 16 + nl;
                    pbase[(size_t)v * D_ + d] = acc[mt][nt][r];
                }
    }

    // ---------------- device-wide barrier ----------------
    // __syncthreads drains vmcnt(0): all this block's part/cntpart stores have
    // reached L2. tid0's __threadfence (agent scope) writes dirty L2 back so
    // remote XCDs see it; arrival via device-scope atomic.
    __syncthreads();
    if (tid == 0) {
        __threadfence();
        atomicAdd(bar, 1u);
        while (__hip_atomic_load(bar, __ATOMIC_ACQUIRE, __HIP_MEMORY_SCOPE_AGENT)
               < (unsigned)nblk)
            __builtin_amdgcn_s_sleep(8);
        __threadfence();              // acquire side: invalidate stale L1
    }
    __syncthreads();

    // ---------------- reduce + classify phase: one (b,v) row per item -------
    for (int row = blockIdx.x; row < B_ * V_; row += nblk) {
        const int b = row >> 6;
        const int v = row & (V_ - 1);

        __syncthreads();              // mean[]/scnt reuse guard across rows
        if (tid == 0) scnt = 0u;
        __syncthreads();
        if (tid < SLICES)
            atomicAdd(&scnt, cntpart[(tid * B_ + b) * V_ + v]);

        float s[3];
        #pragma unroll
        for (int j = 0; j < 3; ++j) {
            const int d = tid + j * 256;
            float a = 0.f;
            #pragma unroll
            for (int sl = 0; sl < SLICES; ++sl)
                a += __builtin_nontemporal_load(
                    &part[((size_t)(sl * B_ + b) * V_ + v) * D_ + d]);
            s[j] = a;
        }
        __syncthreads();              // scnt complete
        const unsigned int c = scnt;
        const float inv = 1.f / (float)(c > 1u ? c : 1u);
        #pragma unroll
        for (int j = 0; j < 3; ++j) mean[tid + j * 256] = s[j] * inv;
        __syncthreads();              // means visible

        const bool present = (c > 0u) && (v > 0);
        for (int l = wave; l < L_; l += 4) {
            const float* wrow = Wm + l * D_;
            float p = 0.f;
            #pragma unroll
            for (int j = 0; j < 12; ++j) {
                const int d = lane + 64 * j;
                p += mean[d] * wrow[d];
            }
            #pragma unroll
            for (int off = 32; off > 0; off >>= 1) p += __shfl_down(p, off);
            if (lane == 0) out[row * L_ + l] = present ? (p + bias[l]) : 0.f;
        }
    }
}

extern "C" void kernel_launch(void* const* d_in, const int* in_sizes, int n_in,
                              void* d_out, int out_size, void* d_ws, size_t ws_size,
                              hipStream_t stream) {
    // setup_inputs order: hidden_states, W, b, input_ids
    const float* h    = (const float*)d_in[0];
    const float* Wm   = (const float*)d_in[1];
    const float* bias = (const float*)d_in[2];
    const int*   ids  = (const int*)d_in[3];
    float* out = (float*)d_out;

    // Workspace: [SLICES][B][V][D] fp32 partials, [SLICES][B][V] u32 counts,
    // then the barrier counter (needs explicit init: ws is poisoned per iter).
    float* part = (float*)d_ws;
    unsigned int* cntpart =
        (unsigned int*)(part + (size_t)SLICES * B_ * V_ * D_);
    unsigned int* bar = cntpart + SLICES * B_ * V_;

    // Co-residency: grid = min(2 * numCU, NITEMS); __launch_bounds__(256,2)
    // guarantees 2 blocks/CU fit. Queried once (host-side attribute reads are
    // graph-capture safe).
    static int nblk = 0;
    if (nblk == 0) {
        int dev = 0, cus = 0;
        hipGetDevice(&dev);
        hipDeviceGetAttribute(&cus, hipDeviceAttributeMultiprocessorCount, dev);
        nblk = 2 * cus;
        if (nblk > NITEMS || nblk <= 0) nblk = NITEMS;
    }

    hipMemsetAsync(bar, 0, 64, stream);
    fused_kernel<<<dim3(nblk), 256, 0, stream>>>(
        h, ids, Wm, bias, out, part, cntpart, bar, nblk);
}

// Round 2
// 306.417 us; speedup vs baseline: 1.2457x; 1.2457x over previous
//
#include <hip/hip_runtime.h>

// Problem constants (fixed by the reference):
#define B_ 8
#define S_ 8192
#define D_ 768
#define V_ 64
#define L_ 26

typedef __attribute__((ext_vector_type(8))) short short8;   // 8 bf16 (4 VGPRs)
typedef __attribute__((ext_vector_type(4))) float floatx4;  // MFMA C/D

#define TOKS 256               // tokens (K) per block
#define SLICES (S_ / TOKS)     // 32 K-slices -> partial-sum planes
#define NSL  48                // d-columns (N) per wave = 3 tiles of 16

// sums[b] = OneHot(ids[b])^T @ H[b] as bf16 MFMA with exact one-hot A and
// hi/lo-split B (error ~2^-16 relative). No LDS staging, no atomics:
// each block writes its partial tile to part[slice][b][v][d] with plain
// stores (ws needs no zero-init). Blocks with blockIdx.y==0 also emit the
// per-slice id histogram. grid = (32, 4, 8) = 1024 blocks -> 4 blk/CU
// (4 waves/SIMD: doubled vs the 512-block version to hide HBM latency on
// the strided h reads, which profiling showed to be the pool bottleneck).
__global__ __launch_bounds__(256, 4) void pool_mfma_kernel(
    const float* __restrict__ h, const int* __restrict__ ids,
    float* __restrict__ part, unsigned int* __restrict__ cntpart)
{
    __shared__ unsigned int cnt[V_];

    const int tid  = threadIdx.x;
    const int lane = tid & 63;
    const int wave = tid >> 6;
    const int nl   = lane & 15;   // n (B) / m (A) index within a 16-tile
    const int quad = lane >> 4;   // k-quadrant: lane covers k = quad*8 + j

    const int b     = blockIdx.z;
    const int slice = blockIdx.x;
    const int k0    = slice * TOKS;
    const int n0    = blockIdx.y * (4 * NSL) + wave * NSL;

    const int*   idrow = ids + b * S_ + k0;
    const float* hrow  = h + ((size_t)b * S_ + k0) * D_ + n0;

    // Per-slice histogram (only the y==0 plane does it; non-atomic flush).
    if (blockIdx.y == 0) {
        if (tid < V_) cnt[tid] = 0u;
        __syncthreads();
        if (tid < TOKS / 4) {
            const int4 q = ((const int4*)idrow)[tid];
            atomicAdd(&cnt[q.x], 1u); atomicAdd(&cnt[q.y], 1u);
            atomicAdd(&cnt[q.z], 1u); atomicAdd(&cnt[q.w], 1u);
        }
        __syncthreads();
        if (tid < V_) cntpart[(slice * B_ + b) * V_ + tid] = cnt[tid];
    }

    floatx4 acc[4][3];
    #pragma unroll
    for (int mt = 0; mt < 4; ++mt)
        #pragma unroll
        for (int nt = 0; nt < 3; ++nt) acc[mt][nt] = (floatx4)0.f;

    for (int ks = 0; ks < TOKS; ks += 32) {
        const int kb = ks + quad * 8;
        // this quad's 8 token ids (two aligned int4 loads, L1-broadcast)
        const int4* ip = (const int4*)(idrow + kb);
        const int4 i0 = ip[0], i1 = ip[1];
        const int idv[8] = {i0.x, i0.y, i0.z, i0.w, i1.x, i1.y, i1.z, i1.w};

        // Issue ALL 24 h-loads of this k-step before any dependent VALU:
        // maximizes loads-in-flight per wave (memory-level parallelism).
        float f[3][8];
        #pragma unroll
        for (int nt = 0; nt < 3; ++nt) {
            const float* bp = hrow + (size_t)kb * D_ + nt * 16 + nl;
            #pragma unroll
            for (int j = 0; j < 8; ++j) f[nt][j] = bp[(size_t)j * D_];
        }

        // A fragments (one-hot, exact in bf16): A[m=mt*16+nl][k=quad*8+j].
        // Factored compare: id==mt*16+nl  <=>  (id&15)==nl && (id>>4)==mt.
        short8 afrag[4];
        #pragma unroll
        for (int j = 0; j < 8; ++j) {
            const int id  = idv[j];
            const short e = ((id & 15) == nl) ? (short)0x3F80 : (short)0;
            const int hi4 = id >> 4;
            #pragma unroll
            for (int mt = 0; mt < 4; ++mt)
                afrag[mt][j] = (hi4 == mt) ? e : (short)0;
        }

        // B fragments per n-tile: B[k=quad*8+j][n=nt*16+nl], hi/lo bf16 split
        #pragma unroll
        for (int nt = 0; nt < 3; ++nt) {
            short8 bhi, blo;
            #pragma unroll
            for (int j = 0; j < 8; ++j) {
                const unsigned u = __builtin_bit_cast(unsigned, f[nt][j]);
                bhi[j] = (short)(u >> 16);
                const float hif = __builtin_bit_cast(float, u & 0xFFFF0000u);
                const float lof = f[nt][j] - hif;
                blo[j] = (short)(__builtin_bit_cast(unsigned, lof) >> 16);
            }
            #pragma unroll
            for (int mt = 0; mt < 4; ++mt) {
                acc[mt][nt] = __builtin_amdgcn_mfma_f32_16x16x32_bf16(
                    afrag[mt], bhi, acc[mt][nt], 0, 0, 0);
                acc[mt][nt] = __builtin_amdgcn_mfma_f32_16x16x32_bf16(
                    afrag[mt], blo, acc[mt][nt], 0, 0, 0);
            }
        }
    }

    // Flush partial sums (plain stores). C/D layout: col=lane&15, row=quad*4+r.
    float* pbase = part + ((size_t)(slice * B_ + b) * V_) * D_;
    #pragma unroll
    for (int mt = 0; mt < 4; ++mt)
        #pragma unroll
        for (int nt = 0; nt < 3; ++nt)
            #pragma unroll
            for (int r = 0; r < 4; ++r) {
                const int v = mt * 16 + quad * 4 + r;
                const int d = n0 + nt * 16 + nl;
                pbase[(size_t)v * D_ + d] = acc[mt][nt][r];
            }
}

// Reduce 32 partial planes, mean, classify (26 dots of length 768), mask.
// One block (4 waves) per (batch, symbol) row.
__global__ __launch_bounds__(256) void reduce_finalize_kernel(
    const float* __restrict__ part, const unsigned int* __restrict__ cntpart,
    const float* __restrict__ Wm, const float* __restrict__ bias,
    float* __restrict__ out)
{
    __shared__ float mean[D_];
    __shared__ unsigned int scnt;

    const int tid = threadIdx.x;
    const int bv  = blockIdx.x;
    const int b   = bv >> 6;
    const int v   = bv & (V_ - 1);

    if (tid == 0) scnt = 0u;
    __syncthreads();
    if (tid < SLICES)
        atomicAdd(&scnt, cntpart[(tid * B_ + b) * V_ + v]);

    float s[3];
    #pragma unroll
    for (int j = 0; j < 3; ++j) {
        const int d = tid + j * 256;
        float a = 0.f;
        #pragma unroll
        for (int sl = 0; sl < SLICES; ++sl)
            a += part[((size_t)(sl * B_ + b) * V_ + v) * D_ + d];
        s[j] = a;
    }
    __syncthreads();               // scnt complete
    const unsigned int c = scnt;
    const float inv = 1.f / (float)(c > 1u ? c : 1u);
    #pragma unroll
    for (int j = 0; j < 3; ++j) mean[tid + j * 256] = s[j] * inv;
    __syncthreads();               // means visible

    const bool present = (c > 0u) && (v > 0);
    const int lane = tid & 63;
    const int wave = tid >> 6;
    for (int l = wave; l < L_; l += 4) {
        const float* wrow = Wm + l * D_;
        float p = 0.f;
        #pragma unroll
        for (int j = 0; j < 12; ++j) {
            const int d = lane + 64 * j;
            p += mean[d] * wrow[d];
        }
        #pragma unroll
        for (int off = 32; off > 0; off >>= 1) p += __shfl_down(p, off);
        if (lane == 0) out[bv * L_ + l] = present ? (p + bias[l]) : 0.f;
    }
}

extern "C" void kernel_launch(void* const* d_in, const int* in_sizes, int n_in,
                              void* d_out, int out_size, void* d_ws, size_t ws_size,
                              hipStream_t stream) {
    // setup_inputs order: hidden_states, W, b, input_ids
    const float* h    = (const float*)d_in[0];
    const float* Wm   = (const float*)d_in[1];
    const float* bias = (const float*)d_in[2];
    const int*   ids  = (const int*)d_in[3];
    float* out = (float*)d_out;

    // Workspace: [SLICES][B][V][D] fp32 partial sums, [SLICES][B][V] u32 counts.
    // Every element is written before being read -> no zero-init needed.
    float* part = (float*)d_ws;
    unsigned int* cntpart =
        (unsigned int*)(part + (size_t)SLICES * B_ * V_ * D_);

    dim3 grid1(SLICES, D_ / (4 * NSL), B_);   // (32, 4, 8) = 1024 blocks
    pool_mfma_kernel<<<grid1, 256, 0, stream>>>(h, ids, part, cntpart);

    reduce_finalize_kernel<<<B_ * V_, 256, 0, stream>>>(
        part, cntpart, Wm, bias, out);
}

// Round 3
// 296.471 us; speedup vs baseline: 1.2875x; 1.0335x over previous
//
#include <hip/hip_runtime.h>

// Problem constants (fixed by the reference):
#define B_ 8
#define S_ 8192
#define D_ 768
#define V_ 64
#define L_ 26

typedef __attribute__((ext_vector_type(8))) short short8;   // 8 bf16 (4 VGPRs)
typedef __attribute__((ext_vector_type(4))) float floatx4;  // MFMA C/D

#define TOKS 512               // tokens (K) per block
#define SLICES (S_ / TOKS)     // 16 K-slices -> partial-sum planes
#define NSL  48                // d-columns (N) per wave = 3 tiles of 16
#define KSTEPS (TOKS / 32)     // 16 k-steps per block

// Load one k-step's inputs: 2x int4 ids + 24 strided h floats, batched so all
// 26 loads issue back-to-back (max loads in flight per wave).
__device__ __forceinline__ void load_kstep(
    const float* __restrict__ hrow, const int* __restrict__ idrow,
    int kk, int quad, int nl, float (&f)[3][8], int4& i0, int4& i1)
{
    const int kb = kk * 32 + quad * 8;
    const int4* ip = (const int4*)(idrow + kb);
    i0 = ip[0]; i1 = ip[1];
    #pragma unroll
    for (int nt = 0; nt < 3; ++nt) {
        const float* bp = hrow + (size_t)kb * D_ + nt * 16 + nl;
        #pragma unroll
        for (int j = 0; j < 8; ++j) f[nt][j] = bp[(size_t)j * D_];
    }
}

// Consume one k-step: build one-hot A fragments, hi/lo bf16-split B, 24 MFMAs.
__device__ __forceinline__ void compute_kstep(
    const float (&f)[3][8], int4 i0, int4 i1, int nl, floatx4 (&acc)[4][3])
{
    const int idv[8] = {i0.x, i0.y, i0.z, i0.w, i1.x, i1.y, i1.z, i1.w};

    // A fragments (one-hot, exact in bf16): A[m=mt*16+nl][k=quad*8+j].
    // Factored compare: id==mt*16+nl  <=>  (id&15)==nl && (id>>4)==mt.
    short8 afrag[4];
    #pragma unroll
    for (int j = 0; j < 8; ++j) {
        const int id  = idv[j];
        const short e = ((id & 15) == nl) ? (short)0x3F80 : (short)0;
        const int hi4 = id >> 4;
        #pragma unroll
        for (int mt = 0; mt < 4; ++mt)
            afrag[mt][j] = (hi4 == mt) ? e : (short)0;
    }

    // B fragments per n-tile: B[k=quad*8+j][n=nt*16+nl], hi/lo bf16 split
    #pragma unroll
    for (int nt = 0; nt < 3; ++nt) {
        short8 bhi, blo;
        #pragma unroll
        for (int j = 0; j < 8; ++j) {
            const unsigned u = __builtin_bit_cast(unsigned, f[nt][j]);
            bhi[j] = (short)(u >> 16);
            const float hif = __builtin_bit_cast(float, u & 0xFFFF0000u);
            const float lof = f[nt][j] - hif;
            blo[j] = (short)(__builtin_bit_cast(unsigned, lof) >> 16);
        }
        #pragma unroll
        for (int mt = 0; mt < 4; ++mt) {
            acc[mt][nt] = __builtin_amdgcn_mfma_f32_16x16x32_bf16(
                afrag[mt], bhi, acc[mt][nt], 0, 0, 0);
            acc[mt][nt] = __builtin_amdgcn_mfma_f32_16x16x32_bf16(
                afrag[mt], blo, acc[mt][nt], 0, 0, 0);
        }
    }
}

// sums[b] = OneHot(ids[b])^T @ H[b] as bf16 MFMA. Explicit 2-stage register
// software pipeline over k-steps (named A/B buffers, static indexing): step
// k+1's 26 loads are issued BEFORE step k's convert+MFMA, so HBM latency
// hides under ~560 VALU cycles of compute. grid = (16,4,8) = 512 blocks,
// 2 blk/CU (round-0 proven config: lowest part traffic).
__global__ __launch_bounds__(256, 2) void pool_mfma_kernel(
    const float* __restrict__ h, const int* __restrict__ ids,
    float* __restrict__ part, unsigned int* __restrict__ cntpart)
{
    __shared__ unsigned int cnt[V_];

    const int tid  = threadIdx.x;
    const int lane = tid & 63;
    const int wave = tid >> 6;
    const int nl   = lane & 15;   // n (B) / m (A) index within a 16-tile
    const int quad = lane >> 4;   // k-quadrant: lane covers k = quad*8 + j

    const int b     = blockIdx.z;
    const int slice = blockIdx.x;
    const int k0    = slice * TOKS;
    const int n0    = blockIdx.y * (4 * NSL) + wave * NSL;

    const int*   idrow = ids + b * S_ + k0;
    const float* hrow  = h + ((size_t)b * S_ + k0) * D_ + n0;

    // Per-slice histogram (only the y==0 plane does it; non-atomic flush).
    if (blockIdx.y == 0) {
        if (tid < V_) cnt[tid] = 0u;
        __syncthreads();
        if (tid < TOKS / 4) {
            const int4 q = ((const int4*)idrow)[tid];
            atomicAdd(&cnt[q.x], 1u); atomicAdd(&cnt[q.y], 1u);
            atomicAdd(&cnt[q.z], 1u); atomicAdd(&cnt[q.w], 1u);
        }
        __syncthreads();
        if (tid < V_) cntpart[(slice * B_ + b) * V_ + tid] = cnt[tid];
    }

    floatx4 acc[4][3];
    #pragma unroll
    for (int mt = 0; mt < 4; ++mt)
        #pragma unroll
        for (int nt = 0; nt < 3; ++nt) acc[mt][nt] = (floatx4)0.f;

    // 2-stage pipeline, manual 2x unroll (KSTEPS=16 is even).
    float fA[3][8], fB[3][8];
    int4 iA0, iA1, iB0, iB1;
    load_kstep(hrow, idrow, 0, quad, nl, fA, iA0, iA1);
    #pragma unroll
    for (int ks = 0; ks < KSTEPS; ks += 2) {
        load_kstep(hrow, idrow, ks + 1, quad, nl, fB, iB0, iB1);
        compute_kstep(fA, iA0, iA1, nl, acc);
        if (ks + 2 < KSTEPS)
            load_kstep(hrow, idrow, ks + 2, quad, nl, fA, iA0, iA1);
        compute_kstep(fB, iB0, iB1, nl, acc);
    }

    // Flush partial sums (plain stores). C/D layout: col=lane&15, row=quad*4+r.
    float* pbase = part + ((size_t)(slice * B_ + b) * V_) * D_;
    #pragma unroll
    for (int mt = 0; mt < 4; ++mt)
        #pragma unroll
        for (int nt = 0; nt < 3; ++nt)
            #pragma unroll
            for (int r = 0; r < 4; ++r) {
                const int v = mt * 16 + quad * 4 + r;
                const int d = n0 + nt * 16 + nl;
                pbase[(size_t)v * D_ + d] = acc[mt][nt][r];
            }
}

// Reduce 16 partial planes, mean, classify (26 dots of length 768), mask.
// One block (4 waves) per (batch, symbol) row. part reads are float4
// (threads 0..191 cover 768 d): same bytes, 4x fewer VMEM instructions,
// identical per-d summation order (bit-identical result).
__global__ __launch_bounds__(256) void reduce_finalize_kernel(
    const float* __restrict__ part, const unsigned int* __restrict__ cntpart,
    const float* __restrict__ Wm, const float* __restrict__ bias,
    float* __restrict__ out)
{
    __shared__ float mean[D_];
    __shared__ unsigned int scnt;

    const int tid = threadIdx.x;
    const int bv  = blockIdx.x;
    const int b   = bv >> 6;
    const int v   = bv & (V_ - 1);

    if (tid == 0) scnt = 0u;
    __syncthreads();
    if (tid < SLICES)
        atomicAdd(&scnt, cntpart[(tid * B_ + b) * V_ + v]);

    floatx4 s4 = (floatx4)0.f;
    if (tid < D_ / 4) {
        #pragma unroll
        for (int sl = 0; sl < SLICES; ++sl) {
            const floatx4 p4 = *(const floatx4*)
                &part[((size_t)(sl * B_ + b) * V_ + v) * D_ + 4 * tid];
            s4 += p4;
        }
    }
    __syncthreads();               // scnt complete
    const unsigned int c = scnt;
    const float inv = 1.f / (float)(c > 1u ? c : 1u);
    if (tid < D_ / 4) {
        #pragma unroll
        for (int x = 0; x < 4; ++x) mean[4 * tid + x] = s4[x] * inv;
    }
    __syncthreads();               // means visible

    const bool present = (c > 0u) && (v > 0);
    const int lane = tid & 63;
    const int wave = tid >> 6;
    for (int l = wave; l < L_; l += 4) {
        const float* wrow = Wm + l * D_;
        float p = 0.f;
        #pragma unroll
        for (int j = 0; j < 12; ++j) {
            const int d = lane + 64 * j;
            p += mean[d] * wrow[d];
        }
        #pragma unroll
        for (int off = 32; off > 0; off >>= 1) p += __shfl_down(p, off);
        if (lane == 0) out[bv * L_ + l] = present ? (p + bias[l]) : 0.f;
    }
}

extern "C" void kernel_launch(void* const* d_in, const int* in_sizes, int n_in,
                              void* d_out, int out_size, void* d_ws, size_t ws_size,
                              hipStream_t stream) {
    // setup_inputs order: hidden_states, W, b, input_ids
    const float* h    = (const float*)d_in[0];
    const float* Wm   = (const float*)d_in[1];
    const float* bias = (const float*)d_in[2];
    const int*   ids  = (const int*)d_in[3];
    float* out = (float*)d_out;

    // Workspace: [SLICES][B][V][D] fp32 partial sums, [SLICES][B][V] u32 counts.
    // Every element is written before being read -> no zero-init needed.
    float* part = (float*)d_ws;
    unsigned int* cntpart =
        (unsigned int*)(part + (size_t)SLICES * B_ * V_ * D_);

    dim3 grid1(SLICES, D_ / (4 * NSL), B_);   // (16, 4, 8) = 512 blocks
    pool_mfma_kernel<<<grid1, 256, 0, stream>>>(h, ids, part, cntpart);

    reduce_finalize_kernel<<<B_ * V_, 256, 0, stream>>>(
        part, cntpart, Wm, bias, out);
}

// Round 4
// 284.103 us; speedup vs baseline: 1.3436x; 1.0435x over previous
//
#include <hip/hip_runtime.h>

// Problem constants (fixed by the reference):
#define B_ 8
#define S_ 8192
#define D_ 768
#define V_ 64
#define L_ 26

typedef __attribute__((ext_vector_type(8))) short short8;   // 8 bf16 (4 VGPRs)
typedef __attribute__((ext_vector_type(4))) float floatx4;  // MFMA C/D

#define TOKS 512               // tokens (K) per block
#define SLICES (S_ / TOKS)     // 16 K-slices -> partial-sum planes
#define NSL  48                // d-columns (N) per wave = 3 tiles of 16
#define BLKN (4 * NSL)         // 192 d-columns per block
#define KSTEPS (TOKS / 32)     // 16 k-steps per block
#define TILE_FLOATS (32 * BLKN)        // 6144 floats = 24576 B per k-step tile
#define CH_PER_THREAD 6                // 1536 16B-chunks / 256 threads

// Consume one k-step: build one-hot A fragments, hi/lo bf16-split B, 24 MFMAs.
// (identical math to the verified round-0/3 kernels)
__device__ __forceinline__ void compute_kstep(
    const float (&f)[3][8], int4 i0, int4 i1, int nl, floatx4 (&acc)[4][3])
{
    const int idv[8] = {i0.x, i0.y, i0.z, i0.w, i1.x, i1.y, i1.z, i1.w};

    short8 afrag[4];
    #pragma unroll
    for (int j = 0; j < 8; ++j) {
        const int id  = idv[j];
        const short e = ((id & 15) == nl) ? (short)0x3F80 : (short)0;
        const int hi4 = id >> 4;
        #pragma unroll
        for (int mt = 0; mt < 4; ++mt)
            afrag[mt][j] = (hi4 == mt) ? e : (short)0;
    }

    #pragma unroll
    for (int nt = 0; nt < 3; ++nt) {
        short8 bhi, blo;
        #pragma unroll
        for (int j = 0; j < 8; ++j) {
            const unsigned u = __builtin_bit_cast(unsigned, f[nt][j]);
            bhi[j] = (short)(u >> 16);
            const float hif = __builtin_bit_cast(float, u & 0xFFFF0000u);
            const float lof = f[nt][j] - hif;
            blo[j] = (short)(__builtin_bit_cast(unsigned, lof) >> 16);
        }
        #pragma unroll
        for (int mt = 0; mt < 4; ++mt) {
            acc[mt][nt] = __builtin_amdgcn_mfma_f32_16x16x32_bf16(
                afrag[mt], bhi, acc[mt][nt], 0, 0, 0);
            acc[mt][nt] = __builtin_amdgcn_mfma_f32_16x16x32_bf16(
                afrag[mt], blo, acc[mt][nt], 0, 0, 0);
        }
    }
}

// Pool via the minimum 2-phase LDS-staged loop: per k-step, stage(next tile)
// with global_load_lds width=16 (1 KB contiguous per wave-instr, async DMA,
// no VGPR round trip), then compute current tile from LDS; one
// __syncthreads (implicit vmcnt(0) drain) per step. Double-buffered 24.5KB
// tiles; ids staged to LDS once. grid (16,4,8)=512 blocks, 2 blk/CU.
__global__ __launch_bounds__(256, 2) void pool_mfma_kernel(
    const float* __restrict__ h, const int* __restrict__ ids,
    float* __restrict__ part, unsigned int* __restrict__ cntpart)
{
    __shared__ __align__(16) float tile[2][TILE_FLOATS];   // 49152 B
    __shared__ __align__(16) int ids_lds[TOKS];            // 2048 B
    __shared__ unsigned int cnt[V_];

    const int tid  = threadIdx.x;
    const int lane = tid & 63;
    const int wave = tid >> 6;
    const int nl   = lane & 15;   // n (B) / m (A) index within a 16-tile
    const int quad = lane >> 4;   // k-quadrant: lane covers k = quad*8 + j

    const int b     = blockIdx.z;
    const int slice = blockIdx.x;
    const int k0    = slice * TOKS;
    const int n0    = blockIdx.y * BLKN + wave * NSL;

    const int*  idrow = ids + b * S_ + k0;
    const char* hblk  = (const char*)
        (h + ((size_t)b * S_ + k0) * D_ + blockIdx.y * BLKN);

    // Per-thread stage chunk -> global byte offset within the 32x192 tile.
    // Chunk C = (t*4 + wave)*64 + lane; LDS image is linear (row-major,
    // stride 192 floats, no pad -> exact 6 chunks/thread, wave-linear dest).
    int goff[CH_PER_THREAD];
    #pragma unroll
    for (int t = 0; t < CH_PER_THREAD; ++t) {
        const int C   = (t * 4 + wave) * 64 + lane;
        const int row = C / 48;          // token within step
        const int c16 = C % 48;          // 16B chunk within row
        goff[t] = row * (D_ * 4) + c16 * 16;
    }

    // Stage ids (2048 B, wave 0) + tile for k-step 0 into buf 0.
    if (wave == 0) {
        #pragma unroll
        for (int i = 0; i < 2; ++i)
            __builtin_amdgcn_global_load_lds(
                (const unsigned int*)(idrow + i * 256 + lane * 4),
                (unsigned int*)&ids_lds[i * 256], 16, 0, 0);
    }
    #pragma unroll
    for (int t = 0; t < CH_PER_THREAD; ++t)
        __builtin_amdgcn_global_load_lds(
            (const unsigned int*)(hblk + goff[t]),
            (unsigned int*)&tile[0][(t * 4 + wave) * 256], 16, 0, 0);

    __syncthreads();                 // ids + tile0 resident

    floatx4 acc[4][3];
    #pragma unroll
    for (int mt = 0; mt < 4; ++mt)
        #pragma unroll
        for (int nt = 0; nt < 3; ++nt) acc[mt][nt] = (floatx4)0.f;

    #pragma unroll 2
    for (int ks = 0; ks < KSTEPS; ++ks) {
        // Issue stage of k-step ks+1 into the other buffer; these 6 loads
        // stay in flight under compute(ks) and are drained by the barrier.
        if (ks + 1 < KSTEPS) {
            const char* gs = hblk + (ks + 1) * (32 * D_ * 4);
            #pragma unroll
            for (int t = 0; t < CH_PER_THREAD; ++t)
                __builtin_amdgcn_global_load_lds(
                    (const unsigned int*)(gs + goff[t]),
                    (unsigned int*)&tile[(ks + 1) & 1][(t * 4 + wave) * 256],
                    16, 0, 0);
        }

        // Compute k-step ks from tile[ks&1].
        const float* tb = &tile[ks & 1][0];
        const int kb = ks * 32 + quad * 8;
        const int4 i0 = *(const int4*)&ids_lds[kb];
        const int4 i1 = *(const int4*)&ids_lds[kb + 4];
        float f[3][8];
        #pragma unroll
        for (int nt = 0; nt < 3; ++nt)
            #pragma unroll
            for (int j = 0; j < 8; ++j)
                f[nt][j] = tb[(quad * 8 + j) * BLKN + wave * NSL + nt * 16 + nl];
        compute_kstep(f, i0, i1, nl, acc);

        __syncthreads();             // drain stage(ks+1), release buffers
    }

    // Per-slice histogram (y==0 planes; ids already in LDS).
    if (blockIdx.y == 0) {
        if (tid < V_) cnt[tid] = 0u;
        __syncthreads();
        if (tid < TOKS / 4) {
            const int4 q = *(const int4*)&ids_lds[tid * 4];
            atomicAdd(&cnt[q.x], 1u); atomicAdd(&cnt[q.y], 1u);
            atomicAdd(&cnt[q.z], 1u); atomicAdd(&cnt[q.w], 1u);
        }
        __syncthreads();
        if (tid < V_) cntpart[(slice * B_ + b) * V_ + tid] = cnt[tid];
    }

    // Flush partial sums (plain stores). C/D layout: col=lane&15, row=quad*4+r.
    float* pbase = part + ((size_t)(slice * B_ + b) * V_) * D_;
    #pragma unroll
    for (int mt = 0; mt < 4; ++mt)
        #pragma unroll
        for (int nt = 0; nt < 3; ++nt)
            #pragma unroll
            for (int r = 0; r < 4; ++r) {
                const int v = mt * 16 + quad * 4 + r;
                const int d = n0 + nt * 16 + nl;
                pbase[(size_t)v * D_ + d] = acc[mt][nt][r];
            }
}

// Reduce 16 partial planes, mean, classify (26 dots of length 768), mask.
// One block (4 waves) per (batch, symbol) row; float4 part reads.
__global__ __launch_bounds__(256) void reduce_finalize_kernel(
    const float* __restrict__ part, const unsigned int* __restrict__ cntpart,
    const float* __restrict__ Wm, const float* __restrict__ bias,
    float* __restrict__ out)
{
    __shared__ float mean[D_];
    __shared__ unsigned int scnt;

    const int tid = threadIdx.x;
    const int bv  = blockIdx.x;
    const int b   = bv >> 6;
    const int v   = bv & (V_ - 1);

    if (tid == 0) scnt = 0u;
    __syncthreads();
    if (tid < SLICES)
        atomicAdd(&scnt, cntpart[(tid * B_ + b) * V_ + v]);

    floatx4 s4 = (floatx4)0.f;
    if (tid < D_ / 4) {
        #pragma unroll
        for (int sl = 0; sl < SLICES; ++sl) {
            const floatx4 p4 = *(const floatx4*)
                &part[((size_t)(sl * B_ + b) * V_ + v) * D_ + 4 * tid];
            s4 += p4;
        }
    }
    __syncthreads();               // scnt complete
    const unsigned int c = scnt;
    const float inv = 1.f / (float)(c > 1u ? c : 1u);
    if (tid < D_ / 4) {
        #pragma unroll
        for (int x = 0; x < 4; ++x) mean[4 * tid + x] = s4[x] * inv;
    }
    __syncthreads();               // means visible

    const bool present = (c > 0u) && (v > 0);
    const int lane = tid & 63;
    const int wave = tid >> 6;
    for (int l = wave; l < L_; l += 4) {
        const float* wrow = Wm + l * D_;
        float p = 0.f;
        #pragma unroll
        for (int j = 0; j < 12; ++j) {
            const int d = lane + 64 * j;
            p += mean[d] * wrow[d];
        }
        #pragma unroll
        for (int off = 32; off > 0; off >>= 1) p += __shfl_down(p, off);
        if (lane == 0) out[bv * L_ + l] = present ? (p + bias[l]) : 0.f;
    }
}

extern "C" void kernel_launch(void* const* d_in, const int* in_sizes, int n_in,
                              void* d_out, int out_size, void* d_ws, size_t ws_size,
                              hipStream_t stream) {
    // setup_inputs order: hidden_states, W, b, input_ids
    const float* h    = (const float*)d_in[0];
    const float* Wm   = (const float*)d_in[1];
    const float* bias = (const float*)d_in[2];
    const int*   ids  = (const int*)d_in[3];
    float* out = (float*)d_out;

    // Workspace: [SLICES][B][V][D] fp32 partial sums, [SLICES][B][V] u32 counts.
    // Every element is written before being read -> no zero-init needed.
    float* part = (float*)d_ws;
    unsigned int* cntpart =
        (unsigned int*)(part + (size_t)SLICES * B_ * V_ * D_);

    dim3 grid1(SLICES, D_ / BLKN, B_);   // (16, 4, 8) = 512 blocks
    pool_mfma_kernel<<<grid1, 256, 0, stream>>>(h, ids, part, cntpart);

    reduce_finalize_kernel<<<B_ * V_, 256, 0, stream>>>(
        part, cntpart, Wm, bias, out);
}